// Round 13
// baseline (203.267 us; speedup 1.0000x reference)
//
#include <hip/hip_runtime.h>
#include <hip/hip_bf16.h>
#include <math.h>

#define CC 32
#define LL 16
#define HH 64
#define WW 64
#define WF 33
#define RR 16
#define PI_F 3.14159265358979323846f

typedef __attribute__((ext_vector_type(8))) short short8;
typedef __attribute__((ext_vector_type(4))) float f32x4;

// ---- workspace layout (floats). Regions reused across phases. ----
#define OFF_F1      0          // f1 packed bf16 [l][h][w][ci]; later reused as Y2 (fp32)
#define OFF_COLSUM  2097152    // 32768    [l][c][w]
#define OFF_FEAT    2130944    // 16896    [l][wf][c]
#define OFF_XFR     2958848    // 1081344 u32: packed bf16 complex XF [l][c][f][h]
#define OFF_XFI     4040192    // (free; part of Y1 overlap)
#define OFF_YFR     5121536    // 1081344 u32: packed bf16 complex YF [l][c][f][h]
#define OFF_YFI     6202880    // (free)
#define OFF_PART    2958848    // 2097152  conv2 partials (dead XF region, consumed pre-rfft)
#define OFF_Y1      2958848    // 2097152  irfft out (overlaps dead XF region)
#define OFF_Y2      0          // 2097152  pif raw out (overlaps dead F1)
#define OFF_GNM     7284224    // 64
#define OFF_GNR     7284288    // 64
#define OFF_YM      7284352    // 32768    [l][h][c] RAW w-means of Y2
#define OFF_GATE    7317120    // 32768
#define OFF_WVEC    7349888    // 66
#define OFF_WT      7350016    // ushort region: conv(18432) + AT(10240) + BT(12288)
#define OFF_YQ      7370496    // 32768    [l][h][c] row sum-of-squares of Y2
// total ~29.6 MB

__device__ __forceinline__ float sigmoidf_(float x){ return 1.0f/(1.0f+expf(-x)); }
__device__ __forceinline__ unsigned short f2bf(float v){
    __hip_bfloat16 b = __float2bfloat16(v);
    return *reinterpret_cast<unsigned short*>(&b);
}
__device__ __forceinline__ float bf2f(unsigned short u){
    __hip_bfloat16 b = *reinterpret_cast<__hip_bfloat16*>(&u);
    return __bfloat162float(b);
}

// ---- K0: all precompute: wvec, conv weight pack, rfft A-table, irfft B-table ----
__global__ void k_prep0(const float* __restrict__ mix_w, const float* __restrict__ mix_b,
                        const float* __restrict__ rank_scale, const float* __restrict__ proj_w,
                        const float* __restrict__ proj_b,
                        const float* __restrict__ c1w, const float* __restrict__ c2w,
                        float* __restrict__ ws){
    unsigned short* wt = (unsigned short*)(ws + OFF_WT);
    if (blockIdx.x == 0){
        float* wv = ws + OFF_WVEC;
        int t = threadIdx.x;
        if (t < 32){
            float sre=0.f, sim=0.f;
            for (int r=0;r<RR;r++){
                float a = proj_w[r]*rank_scale[r];
                sre += a*mix_w[r*2*RR + t];
                sim += a*mix_w[(RR+r)*2*RR + t];
            }
            wv[t] = sre; wv[32+t] = sim;
        }
        if (t == 0){
            float cre=0.f, cim=0.f;
            for (int r=0;r<RR;r++){
                float a = proj_w[r]*rank_scale[r];
                cre += a*mix_b[r];
                cim += a*mix_b[RR+r];
            }
            wv[64] = cre + proj_b[0]; wv[65] = cim;
        }
        return;
    }
    int i = (blockIdx.x-1)*256 + threadIdx.x;
    if (i < 18432){
        int which = (i >= 9216);
        int j = which ? i - 9216 : i;
        int je   = j & 7;
        int lane = (j >> 3) & 63;
        int ct   = (j >> 9) & 1;
        int tap  = j >> 10;
        int kh = tap/3, kw = tap - kh*3;
        int co = ct*16 + (lane & 15);
        int ci = (lane >> 4)*8 + je;
        const float* cw = which ? c2w : c1w;
        wt[i] = f2bf(cw[((co*CC + ci)*3 + kh)*3 + kw]);
        return;
    }
    i -= 18432;
    if (i < 10240){
        int j = i & 7, lane = (i>>3)&63, cch = (i>>9)&3, t = i>>11;
        int frow = t*16 + (lane & 15);
        int k = ((lane>>4)&3)*8 + j;
        int w = (cch & 1)*32 + k;
        float coef = 0.f;
        if (frow < 33)       coef =  cosf(2.0f*PI_F*(float)(frow*w)/64.0f);
        else if (frow < 66)  coef = -sinf(2.0f*PI_F*(float)((frow-33)*w)/64.0f);
        unsigned short hi = f2bf(coef);
        wt[18432 + i] = (cch < 2) ? hi : f2bf(coef - bf2f(hi));
        return;
    }
    i -= 10240;
    if (i < 12288){
        int wtile = i / 3072;
        int rem = i - wtile*3072;
        int ch = rem >> 9;
        int ll = rem & 511;
        int lane = ll >> 3, j = ll & 7;
        int w = wtile*16 + (lane & 15);
        int k = (ch % 3)*32 + ((lane>>4)&3)*8 + j;
        float coef = 0.f;
        if (k < 33){
            float s = (k==0 || k==32) ? 1.f : 2.f;
            coef = s*cosf(2.0f*PI_F*(float)(k*w)/64.0f)*(1.0f/64.0f);
        } else if (k < 66){
            int f = k - 33;
            float s = (f==0 || f==32) ? 1.f : 2.f;
            coef = -s*sinf(2.0f*PI_F*(float)(f*w)/64.0f)*(1.0f/64.0f);
        }
        unsigned short hi = f2bf(coef);
        wt[18432 + 10240 + i] = (ch < 3) ? hi : f2bf(coef - bf2f(hi));
        return;
    }
}

// ---- K1: conv1 (MFMA, bf16). Block = (l, h-tile of 2). Grid 512. ----
__global__ __launch_bounds__(256, 4) void k_conv1m(const float* __restrict__ x,
                                                   const unsigned short* __restrict__ wt,
                                                   const float* __restrict__ cb,
                                                   unsigned short* __restrict__ f1p){
    __shared__ __align__(16) unsigned short xs[4*66*32];  // rows h0-1..h0+2
    __shared__ __align__(16) unsigned short pw[9216];

    const int tid  = threadIdx.x;
    const int l    = blockIdx.x >> 5;
    const int h0   = (blockIdx.x & 31)*2;
    const int wid  = tid >> 6;
    const int lane = tid & 63;
    const int col  = lane & 15;
    const int kgrp = lane >> 4;

    {
        const unsigned int* src = (const unsigned int*)wt;
        unsigned int* dst = (unsigned int*)pw;
        #pragma unroll
        for (int j = 0; j < 18; ++j) dst[tid + j*256] = src[tid + j*256];
    }
    {
        const int rr = tid >> 6;          // 0..3 -> rows h0-1..h0+2
        const int w  = tid & 63;
        int hh = h0 - 1 + rr;
        bool hv = (hh >= 0 && hh < HH);
        const float* sp = x + (long)l*HH*WW + hh*WW + w;
        int wIdx = 1 + w;
        #pragma unroll
        for (int cib = 0; cib < 4; ++cib){
            float v[8];
            #pragma unroll
            for (int k = 0; k < 8; ++k)
                v[k] = hv ? sp[(long)(cib*8 + k)*LL*HH*WW] : 0.f;
            uint4 p;
            p.x = (unsigned)f2bf(v[0]) | ((unsigned)f2bf(v[1])<<16);
            p.y = (unsigned)f2bf(v[2]) | ((unsigned)f2bf(v[3])<<16);
            p.z = (unsigned)f2bf(v[4]) | ((unsigned)f2bf(v[5])<<16);
            p.w = (unsigned)f2bf(v[6]) | ((unsigned)f2bf(v[7])<<16);
            int cs = cib ^ (wIdx & 3);
            *(uint4*)&xs[(rr*66 + wIdx)*32 + cs*8] = p;
        }
    }
    if (tid < 32){   // halo columns
        int row = tid >> 3, rest = tid & 7;
        int wIdx = (rest >> 2) ? 65 : 0;
        int cib = rest & 3;
        *(uint4*)&xs[(row*66 + wIdx)*32 + cib*8] = make_uint4(0,0,0,0);
    }
    __syncthreads();

    #pragma unroll
    for (int u = 0; u < 4; ++u){
        int unit = wid + u*4;             // 0..15
        int hloc = unit >> 3;             // 0..1
        int rem  = unit & 7;
        int ct   = rem >> 2;
        int wt16 = rem & 3;
        int colw = wt16*16 + col;
        f32x4 acc = {0.f,0.f,0.f,0.f};
        #pragma unroll
        for (int kh = 0; kh < 3; ++kh){
            #pragma unroll
            for (int kw = 0; kw < 3; ++kw){
                int wIdx = colw + kw;
                int cs = kgrp ^ (wIdx & 3);
                short8 b = *(const short8*)&xs[((hloc+kh)*66 + wIdx)*32 + cs*8];
                short8 a = *(const short8*)&pw[((kh*3+kw)*2 + ct)*512 + lane*8];
                acc = __builtin_amdgcn_mfma_f32_16x16x32_bf16(a, b, acc, 0, 0, 0);
            }
        }
        int co0 = ct*16 + kgrp*4;
        int h = h0 + hloc;
        float o[4];
        #pragma unroll
        for (int r = 0; r < 4; ++r){
            float v = acc[r] + cb[co0+r];
            o[r] = v * sigmoidf_(v);
        }
        uint2 pk;
        pk.x = (unsigned)f2bf(o[0]) | ((unsigned)f2bf(o[1])<<16);
        pk.y = (unsigned)f2bf(o[2]) | ((unsigned)f2bf(o[3])<<16);
        *(uint2*)&f1p[(((long)l*HH + h)*WW + colw)*32 + co0] = pk;
    }
}

// ---- K2: conv2 (MFMA, bf16) -> PART directly. Grid 512. ----
__global__ __launch_bounds__(256, 4) void k_conv2m(const unsigned short* __restrict__ f1p,
                                                   const unsigned short* __restrict__ wt,
                                                   const float* __restrict__ cb,
                                                   float* __restrict__ ws){
    __shared__ __align__(16) unsigned short xs[4*66*32];
    __shared__ __align__(16) unsigned short pw[9216];

    const int tid  = threadIdx.x;
    const int l    = blockIdx.x >> 5;
    const int h0   = (blockIdx.x & 31)*2;
    const int wid  = tid >> 6;
    const int lane = tid & 63;
    const int col  = lane & 15;
    const int kgrp = lane >> 4;

    {
        const unsigned int* src = (const unsigned int*)wt;
        unsigned int* dst = (unsigned int*)pw;
        #pragma unroll
        for (int j = 0; j < 18; ++j) dst[tid + j*256] = src[tid + j*256];
    }
    {
        const int rr = tid >> 6;
        const int w  = tid & 63;
        int hh = h0 - 1 + rr;
        bool hv = (hh >= 0 && hh < HH);
        const uint4* sp = (const uint4*)&f1p[(((long)l*HH + hh)*WW + w)*32];
        int wIdx = 1 + w;
        #pragma unroll
        for (int cib = 0; cib < 4; ++cib){
            uint4 p = hv ? sp[cib] : make_uint4(0,0,0,0);
            int cs = cib ^ (wIdx & 3);
            *(uint4*)&xs[(rr*66 + wIdx)*32 + cs*8] = p;
        }
    }
    if (tid < 32){
        int row = tid >> 3, rest = tid & 7;
        int wIdx = (rest >> 2) ? 65 : 0;
        int cib = rest & 3;
        *(uint4*)&xs[(row*66 + wIdx)*32 + cib*8] = make_uint4(0,0,0,0);
    }
    __syncthreads();

    #pragma unroll
    for (int u = 0; u < 4; ++u){
        int unit = wid + u*4;
        int hloc = unit >> 3;
        int rem  = unit & 7;
        int ct   = rem >> 2;
        int wt16 = rem & 3;
        int colw = wt16*16 + col;
        f32x4 acc = {0.f,0.f,0.f,0.f};
        #pragma unroll
        for (int kh = 0; kh < 3; ++kh){
            #pragma unroll
            for (int kw = 0; kw < 3; ++kw){
                int wIdx = colw + kw;
                int cs = kgrp ^ (wIdx & 3);
                short8 b = *(const short8*)&xs[((hloc+kh)*66 + wIdx)*32 + cs*8];
                short8 a = *(const short8*)&pw[((kh*3+kw)*2 + ct)*512 + lane*8];
                acc = __builtin_amdgcn_mfma_f32_16x16x32_bf16(a, b, acc, 0, 0, 0);
            }
        }
        int co0 = ct*16 + kgrp*4;
        int h = h0 + hloc;
        float* pp = ws + OFF_PART + ((long)(l*HH + h))*2048 + colw;
        #pragma unroll
        for (int r = 0; r < 4; ++r){
            float v = acc[r] + cb[co0+r];
            pp[(co0+r)*WW] = v * sigmoidf_(v);
        }
    }
}

// ---- K2b: reduce partials over h -> colsum[l][c][w] ----
__global__ void k_colred(float* __restrict__ ws){
    int b = blockIdx.x;
    int l = b >> 5, c = b & 31;
    int w = threadIdx.x;
    const float* p = ws + OFF_PART + (long)l*HH*2048 + c*WW + w;
    float s = 0.f;
    #pragma unroll 8
    for (int h = 0; h < HH; ++h) s += p[h*2048];
    ws[OFF_COLSUM + (l*CC + c)*WW + w] = s;
}

// ---- K3: glob + adaptive pool fused ----
__global__ void k_globfeat(const float* __restrict__ gfc_w, const float* __restrict__ gfc_b,
                           float* __restrict__ ws){
    __shared__ float gs[CC], gl[CC];
    int l = blockIdx.x;
    int tid = threadIdx.x;
    if (tid < 32){
        const float* cs = ws + OFF_COLSUM + (l*CC+tid)*WW;
        float s = 0.f;
        for (int w=0;w<WW;w++) s += cs[w];
        gs[tid] = s;
    }
    __syncthreads();
    if (tid < 32){
        float acc = gfc_b[tid];
        for (int i=0;i<CC;i++) acc += gs[i]*(1.0f/4096.0f)*gfc_w[tid*CC+i];
        gl[tid] = sigmoidf_(acc);
    }
    __syncthreads();
    for (int i = tid; i < WF*CC; i += 256){
        int c = i & 31, wf = i >> 5;
        int s = (wf*64)/33;
        int e = ((wf+1)*64 + 32)/33;
        const float* cs = ws + OFF_COLSUM + (l*CC+c)*WW;
        float sum = 0.f;
        for (int w=s;w<e;w++) sum += cs[w];
        ws[OFF_FEAT + (l*WF+wf)*CC + c] = gl[c] * sum / (64.0f*(float)(e-s));
    }
}

// ---- K6: rfft via MFMA -> packed bf16 complex XF. Block=(l,c). ----
__global__ __launch_bounds__(256, 4) void k_rfftm(const float* __restrict__ x,
                                                  const unsigned short* __restrict__ at,
                                                  float* __restrict__ ws){
    __shared__ __align__(16) unsigned short xs[HH*68];
    __shared__ float fre[33*64];
    __shared__ float fim[33*64];
    int b = blockIdx.x; int l = b >> 5, c = b & 31;
    int tid = threadIdx.x;
    const int wid  = tid >> 6;
    const int lane = tid & 63;
    const int col  = lane & 15;
    const int kgrp = lane >> 4;

    const float* xp = x + (long)(c*LL + l)*HH*WW;
    for (int i = tid; i < HH*WW; i += 256){
        int h = i >> 6, w = i & 63;
        xs[h*68 + w] = f2bf(xp[i]);
    }
    __syncthreads();

    #pragma unroll
    for (int q = 0; q < 5; ++q){
        int unit = wid + q*4;
        int ftile = unit >> 2;
        int htile = unit & 3;
        f32x4 acc = {0.f,0.f,0.f,0.f};
        #pragma unroll
        for (int cch = 0; cch < 4; ++cch){
            short8 a = *(const short8*)&at[(((ftile*4 + cch)*64) + lane)*8];
            short8 bb = *(const short8*)&xs[(htile*16 + col)*68 + (cch & 1)*32 + kgrp*8];
            acc = __builtin_amdgcn_mfma_f32_16x16x32_bf16(a, bb, acc, 0, 0, 0);
        }
        int h = htile*16 + col;
        #pragma unroll
        for (int r = 0; r < 4; ++r){
            int fr = ftile*16 + kgrp*4 + r;
            if (fr < 33)      fre[fr*64 + h] = acc[r];
            else if (fr < 66) fim[(fr-33)*64 + h] = acc[r];
        }
    }
    __syncthreads();
    // packed coalesced store
    unsigned* xfp = (unsigned*)(ws + OFF_XFR) + (long)(l*CC + c)*2112;
    for (int i = tid; i < 2112; i += 256){
        xfp[i] = (unsigned)f2bf(fre[i]) | ((unsigned)f2bf(fim[i]) << 16);
    }
}

// ---- K7: scan over L, HEAD FUSED IN. Packed bf16 complex XF/YF. Block=(c,wf). ----
__global__ __launch_bounds__(256) void k_scan(const float* __restrict__ hw,
                                              const float* __restrict__ hb,
                                              const float* __restrict__ dt,
                                              float* __restrict__ ws){
    __shared__ float lA[LL*RR], lI[LL*RR], lS[LL*RR];
    __shared__ float wv[66];
    __shared__ float lfeat[LL*CC];
    int b = blockIdx.x;
    int c = b / WF, f = b - c*WF;
    int tid = threadIdx.x;
    if (tid < 66) wv[tid] = ws[OFF_WVEC + tid];
    for (int i = tid; i < LL*CC; i += 256){
        int l = i >> 5, ii = i & 31;
        lfeat[i] = ws[OFF_FEAT + (l*WF + f)*CC + ii];
    }
    __syncthreads();
    {
        int l = tid >> 4, r = tid & 15;
        const float* feat = lfeat + l*CC;
        int j0 = (c*RR + r)*3;
        const float* w0 = hw + j0*CC;
        float p0=hb[j0], p1=hb[j0+1], p2=hb[j0+2];
        #pragma unroll 8
        for (int i=0;i<CC;i++){
            float fv = feat[i];
            p0 += fv*w0[i]; p1 += fv*w0[CC+i]; p2 += fv*w0[2*CC+i];
        }
        float nu = fmaxf(p0,0.f) + log1pf(expf(-fabsf(p0)));
        float th = tanhf(p1)*PI_F;
        float sg = sigmoidf_(p2);
        float dtv = dt[l];
        float decay = expf(-nu*dtv);
        float ang = th*dtv;
        lA[tid] = decay*cosf(ang);
        lI[tid] = decay*sinf(ang);
        lS[tid] = sg*(1.0f - expf(-2.0f*fmaxf(dtv,0.f)));
    }
    __syncthreads();
    const int h  = tid >> 2;
    const int rq = tid & 3;
    float sre[4] = {0,0,0,0}, sim[4] = {0,0,0,0};
    float w0_[4], w1_[4], w2_[4], w3_[4];
    #pragma unroll
    for (int q=0;q<4;q++){
        int r = rq*4 + q;
        w0_[q]=wv[r]; w1_[q]=wv[16+r]; w2_[q]=wv[32+r]; w3_[q]=wv[48+r];
    }
    const float cre = wv[64], cim = wv[65];
    const long fh = (long)(c*WF + f)*HH + h;
    const unsigned* xfp = (const unsigned*)(ws + OFF_XFR);
    unsigned* yfp = (unsigned*)(ws + OFF_YFR);
    #pragma unroll 2
    for (int l=0;l<LL;l++){
        unsigned px = xfp[l*(CC*HH*WF) + fh];
        float xr = bf2f((unsigned short)(px & 0xffffu));
        float xi = bf2f((unsigned short)(px >> 16));
        float yr = 0.f, yi = 0.f;
        #pragma unroll
        for (int q=0;q<4;q++){
            int r = rq*4 + q;
            float a = lA[l*16+r], ii = lI[l*16+r], s = lS[l*16+r];
            float nre = a*sre[q] - ii*sim[q] + s*xr;
            float nim = a*sim[q] + ii*sre[q] + s*xi;
            sre[q]=nre; sim[q]=nim;
            yr += w0_[q]*nre + w1_[q]*nim;
            yi += w2_[q]*nre + w3_[q]*nim;
        }
        yr += __shfl_xor(yr, 1); yr += __shfl_xor(yr, 2);
        yi += __shfl_xor(yi, 1); yi += __shfl_xor(yi, 2);
        if (rq == 0){
            yfp[l*(CC*HH*WF) + fh] =
                (unsigned)f2bf(yr + cre) | ((unsigned)f2bf(yi + cim) << 16);
        }
    }
}

// ---- K8: irfft via MFMA from packed bf16 YF. Block=(l,c). ----
__global__ __launch_bounds__(256, 4) void k_irfftm(const unsigned short* __restrict__ btb,
                                                   float* __restrict__ ws){
    __shared__ __align__(16) unsigned short mh[HH*100];
    int b = blockIdx.x; int l = b >> 5, c = b & 31;
    int tid = threadIdx.x;
    const int wid  = tid >> 6;
    const int lane = tid & 63;
    const int col  = lane & 15;
    const int kgrp = lane >> 4;

    const unsigned* yfp = (const unsigned*)(ws + OFF_YFR) + (long)(l*CC + c)*2112;
    for (int i = tid; i < 2112; i += 256){
        unsigned p = yfp[i];
        int f = i >> 6, h = i & 63;
        mh[h*100 + f]      = (unsigned short)(p & 0xffffu);
        mh[h*100 + 33 + f] = (unsigned short)(p >> 16);
    }
    for (int i = tid; i < 64*34; i += 256){
        int h = i / 34, f = 66 + (i - (i/34)*34);
        mh[h*100 + f] = 0;
    }
    __syncthreads();

    float* y1 = ws + OFF_Y1 + (long)(l*CC + c)*HH*WW;
    #pragma unroll
    for (int q = 0; q < 4; ++q){
        int unit = wid + q*4;
        int htile = unit >> 2;
        int wtile = unit & 3;
        f32x4 acc = {0.f,0.f,0.f,0.f};
        #pragma unroll
        for (int ch = 0; ch < 6; ++ch){
            int kof = (ch % 3)*32 + kgrp*8;
            short8 a = *(const short8*)&mh[(htile*16 + col)*100 + kof];
            short8 bb = *(const short8*)&btb[(((wtile*6 + ch)*64) + lane)*8];
            acc = __builtin_amdgcn_mfma_f32_16x16x32_bf16(a, bb, acc, 0, 0, 0);
        }
        int w = wtile*16 + col;
        #pragma unroll
        for (int r = 0; r < 4; ++r){
            int h = htile*16 + kgrp*4 + r;
            y1[h*WW + w] = acc[r];
        }
    }
}

// ---- K9: pif + raw W-mean (YM) + row sum-of-squares (YQ). Block = (l,h). ----
__global__ void k_pif(const float* __restrict__ pw, const float* __restrict__ pb,
                      float* __restrict__ ws){
    __shared__ float row[CC][WW];
    int b = blockIdx.x; int l = b>>6, h = b&63;
    int tid = threadIdx.x;
    for (int k=0;k<8;k++){
        int i = tid + k*256;
        int ci = i>>6, w = i&63;
        row[ci][w] = ws[OFF_Y1 + ((l*CC+ci)*HH + h)*WW + w];
    }
    __syncthreads();
    for (int k=0;k<8;k++){
        int i = tid + k*256;
        int o = i>>6, w = i&63;   // o wave-uniform
        float acc = pb[o];
        #pragma unroll
        for (int ci=0;ci<CC;ci++) acc += pw[o*CC+ci]*row[ci][w];
        ws[OFF_Y2 + ((l*CC+o)*HH + h)*WW + w] = acc;
        float s = acc, q = acc*acc;
        s += __shfl_down(s, 32, 64); q += __shfl_down(q, 32, 64);
        s += __shfl_down(s, 16, 64); q += __shfl_down(q, 16, 64);
        s += __shfl_down(s,  8, 64); q += __shfl_down(q,  8, 64);
        s += __shfl_down(s,  4, 64); q += __shfl_down(q,  4, 64);
        s += __shfl_down(s,  2, 64); q += __shfl_down(q,  2, 64);
        s += __shfl_down(s,  1, 64); q += __shfl_down(q,  1, 64);
        if ((tid & 63) == 0){
            ws[OFF_YM + (l*HH+h)*CC + o] = s*(1.0f/64.0f);
            ws[OFF_YQ + (l*HH+h)*CC + o] = q;
        }
    }
}

// ---- K12: gate, with GN stats fused (per-l, per-h-quad). Grid 64. ----
__global__ void k_gatel(const float* __restrict__ g1w, const float* __restrict__ g1b,
                        const float* __restrict__ g2w, const float* __restrict__ g2b,
                        const float* __restrict__ gnw, const float* __restrict__ gnb,
                        float* __restrict__ ws){
    __shared__ float mus[4], rsd[4];
    __shared__ float ymn[16][CC+1];
    __shared__ float mid[16][4];
    int blk = blockIdx.x;
    int l = blk >> 2, hq = blk & 3;
    int h0 = hq*16;
    int tid = threadIdx.x;

    {
        int g = tid >> 6, j = tid & 63;
        const float* ymp = ws + OFF_YM + (l*HH + j)*CC + g*8;
        const float* yqp = ws + OFF_YQ + (l*HH + j)*CC + g*8;
        float s = 0.f, q = 0.f;
        #pragma unroll
        for (int cc = 0; cc < 8; ++cc){ s += ymp[cc]; q += yqp[cc]; }
        #pragma unroll
        for (int off = 32; off > 0; off >>= 1){
            s += __shfl_down(s, off, 64);
            q += __shfl_down(q, off, 64);
        }
        if (j == 0){
            float mean = s*(1.0f/512.0f);
            float rstd = rsqrtf(q*(1.0f/32768.0f) - mean*mean + 1e-5f);
            mus[g] = mean; rsd[g] = rstd;
            if (hq == 0){ ws[OFF_GNM + l*4+g] = mean; ws[OFF_GNR + l*4+g] = rstd; }
        }
    }
    __syncthreads();
    for (int i = tid; i < 16*CC; i += 256){
        int hh = i >> 5, cidx = i & 31;
        int g = cidx >> 3;
        ymn[hh][cidx] = (ws[OFF_YM + (l*HH + h0 + hh)*CC + cidx] - mus[g])*rsd[g]*gnw[cidx] + gnb[cidx];
    }
    __syncthreads();
    if (tid < 64){
        int hh = tid >> 2, m = tid & 3;
        float a = g1b[m];
        #pragma unroll 8
        for (int i = 0; i < CC; ++i) a += ymn[hh][i]*g1w[m*CC+i];
        mid[hh][m] = a*sigmoidf_(a);
    }
    __syncthreads();
    for (int i = tid; i < 16*CC; i += 256){
        int hh = i >> 5, cidx = i & 31;
        float a = g2b[cidx];
        #pragma unroll
        for (int m = 0; m < 4; ++m) a += mid[hh][m]*g2w[cidx*4+m];
        ws[OFF_GATE + (l*HH + h0 + hh)*CC + cidx] = sigmoidf_(a);
    }
}

// ---- K13: residual (float4), GN applied inline on raw Y2 ----
__global__ void k_final(const float* __restrict__ x, float* __restrict__ out,
                        const float* __restrict__ gnw, const float* __restrict__ gnb,
                        const float* __restrict__ ws){
    int t = blockIdx.x*256 + threadIdx.x;
    int n = t*4;
    int h = (n>>6)&63, l = (n>>12)&15, c = n>>16;
    int g = c>>3;
    float mu = ws[OFF_GNM + l*4+g], rstd = ws[OFF_GNR + l*4+g];
    float gw = gnw[c]*rstd, gb = gnb[c] - mu*gnw[c]*rstd;
    float4 z  = *(const float4*)(ws + OFF_Y2 + (((l*CC+c)*HH+h)*WW) + (n&63));
    float  gt = ws[OFF_GATE + (l*HH+h)*CC + c];
    float4 xv = *(const float4*)(x + n);
    float4 o;
    o.x = xv.x + (z.x*gw+gb)*gt; o.y = xv.y + (z.y*gw+gb)*gt;
    o.z = xv.z + (z.z*gw+gb)*gt; o.w = xv.w + (z.w*gw+gb)*gt;
    *(float4*)(out + n) = o;
}

extern "C" void kernel_launch(void* const* d_in, const int* in_sizes, int n_in,
                              void* d_out, int out_size, void* d_ws, size_t ws_size,
                              hipStream_t stream){
    const float* x    = (const float*)d_in[0];
    const float* dt   = (const float*)d_in[1];
    const float* c1w  = (const float*)d_in[2];
    const float* c1b  = (const float*)d_in[3];
    const float* c2w  = (const float*)d_in[4];
    const float* c2b  = (const float*)d_in[5];
    const float* gfcw = (const float*)d_in[6];
    const float* gfcb = (const float*)d_in[7];
    const float* hw   = (const float*)d_in[8];
    const float* hb   = (const float*)d_in[9];
    const float* mixw = (const float*)d_in[10];
    const float* mixb = (const float*)d_in[11];
    const float* rs   = (const float*)d_in[12];
    const float* pjw  = (const float*)d_in[13];
    const float* pjb  = (const float*)d_in[14];
    const float* pifw = (const float*)d_in[15];
    const float* pifb = (const float*)d_in[16];
    const float* gnw  = (const float*)d_in[17];
    const float* gnb  = (const float*)d_in[18];
    const float* g1w  = (const float*)d_in[19];
    const float* g1b  = (const float*)d_in[20];
    const float* g2w  = (const float*)d_in[21];
    const float* g2b  = (const float*)d_in[22];
    float* ws  = (float*)d_ws;
    float* out = (float*)d_out;
    unsigned short* wt  = (unsigned short*)(ws + OFF_WT);
    unsigned short* at  = wt + 18432;
    unsigned short* btb = wt + 18432 + 10240;
    unsigned short* f1p = (unsigned short*)(ws + OFF_F1);

    k_prep0   <<<161,  256, 0, stream>>>(mixw, mixb, rs, pjw, pjb, c1w, c2w, ws);
    k_conv1m  <<<512,  256, 0, stream>>>(x, wt, c1b, f1p);
    k_conv2m  <<<512,  256, 0, stream>>>(f1p, wt + 9216, c2b, ws);
    k_colred  <<<512,  64,  0, stream>>>(ws);
    k_globfeat<<<16,   256, 0, stream>>>(gfcw, gfcb, ws);
    k_rfftm   <<<512,  256, 0, stream>>>(x, at, ws);
    k_scan    <<<1056, 256, 0, stream>>>(hw, hb, dt, ws);
    k_irfftm  <<<512,  256, 0, stream>>>(btb, ws);
    k_pif     <<<1024, 256, 0, stream>>>(pifw, pifb, ws);
    k_gatel   <<<64,   256, 0, stream>>>(g1w, g1b, g2w, g2b, gnw, gnb, ws);
    k_final   <<<2048, 256, 0, stream>>>(x, out, gnw, gnb, ws);
}

// Round 14
// 200.288 us; speedup vs baseline: 1.0149x; 1.0149x over previous
//
#include <hip/hip_runtime.h>
#include <hip/hip_bf16.h>
#include <math.h>

#define CC 32
#define LL 16
#define HH 64
#define WW 64
#define WF 33
#define RR 16
#define PI_F 3.14159265358979323846f

typedef __attribute__((ext_vector_type(8))) short short8;
typedef __attribute__((ext_vector_type(4))) float f32x4;

// ---- workspace layout (floats). Regions reused across phases. ----
#define OFF_F1      0          // f1 packed bf16 [l][h][w][ci]; later reused as Y2 (fp32)
#define OFF_FEAT    2130944    // 16896    [l][wf][c]
#define OFF_XFR     2958848    // 1081344 u32: packed bf16 complex XF [l][c][f][h]
#define OFF_YFR     5121536    // 1081344 u32: packed bf16 complex YF [l][c][f][h]
#define OFF_PART    2958848    // 1048576  conv2 partials [l][ht32][c*64+w] (dead XF region)
#define OFF_Y1      2958848    // 2097152  irfft out (overlaps dead XF region)
#define OFF_Y2      0          // 2097152  pif raw out (overlaps dead F1)
#define OFF_GNM     7284224    // 64
#define OFF_GNR     7284288    // 64
#define OFF_YM      7284352    // 32768    [l][h][c] RAW w-means of Y2
#define OFF_GATE    7317120    // 32768
#define OFF_WVEC    7349888    // 66
#define OFF_WT      7350016    // ushort region: conv(18432) + AT(10240) + BT(12288)
#define OFF_YQ      7370496    // 32768    [l][h][c] row sum-of-squares of Y2
// total ~29.6 MB

__device__ __forceinline__ float sigmoidf_(float x){ return 1.0f/(1.0f+expf(-x)); }
__device__ __forceinline__ unsigned short f2bf(float v){
    __hip_bfloat16 b = __float2bfloat16(v);
    return *reinterpret_cast<unsigned short*>(&b);
}
__device__ __forceinline__ float bf2f(unsigned short u){
    __hip_bfloat16 b = *reinterpret_cast<__hip_bfloat16*>(&u);
    return __bfloat162float(b);
}

// ---- K0: all precompute: wvec, conv weight pack, rfft A-table, irfft B-table ----
__global__ void k_prep0(const float* __restrict__ mix_w, const float* __restrict__ mix_b,
                        const float* __restrict__ rank_scale, const float* __restrict__ proj_w,
                        const float* __restrict__ proj_b,
                        const float* __restrict__ c1w, const float* __restrict__ c2w,
                        float* __restrict__ ws){
    unsigned short* wt = (unsigned short*)(ws + OFF_WT);
    if (blockIdx.x == 0){
        float* wv = ws + OFF_WVEC;
        int t = threadIdx.x;
        if (t < 32){
            float sre=0.f, sim=0.f;
            for (int r=0;r<RR;r++){
                float a = proj_w[r]*rank_scale[r];
                sre += a*mix_w[r*2*RR + t];
                sim += a*mix_w[(RR+r)*2*RR + t];
            }
            wv[t] = sre; wv[32+t] = sim;
        }
        if (t == 0){
            float cre=0.f, cim=0.f;
            for (int r=0;r<RR;r++){
                float a = proj_w[r]*rank_scale[r];
                cre += a*mix_b[r];
                cim += a*mix_b[RR+r];
            }
            wv[64] = cre + proj_b[0]; wv[65] = cim;
        }
        return;
    }
    int i = (blockIdx.x-1)*256 + threadIdx.x;
    if (i < 18432){
        int which = (i >= 9216);
        int j = which ? i - 9216 : i;
        int je   = j & 7;
        int lane = (j >> 3) & 63;
        int ct   = (j >> 9) & 1;
        int tap  = j >> 10;
        int kh = tap/3, kw = tap - kh*3;
        int co = ct*16 + (lane & 15);
        int ci = (lane >> 4)*8 + je;
        const float* cw = which ? c2w : c1w;
        wt[i] = f2bf(cw[((co*CC + ci)*3 + kh)*3 + kw]);
        return;
    }
    i -= 18432;
    if (i < 10240){
        int j = i & 7, lane = (i>>3)&63, cch = (i>>9)&3, t = i>>11;
        int frow = t*16 + (lane & 15);
        int k = ((lane>>4)&3)*8 + j;
        int w = (cch & 1)*32 + k;
        float coef = 0.f;
        if (frow < 33)       coef =  cosf(2.0f*PI_F*(float)(frow*w)/64.0f);
        else if (frow < 66)  coef = -sinf(2.0f*PI_F*(float)((frow-33)*w)/64.0f);
        unsigned short hi = f2bf(coef);
        wt[18432 + i] = (cch < 2) ? hi : f2bf(coef - bf2f(hi));
        return;
    }
    i -= 10240;
    if (i < 12288){
        int wtile = i / 3072;
        int rem = i - wtile*3072;
        int ch = rem >> 9;
        int ll = rem & 511;
        int lane = ll >> 3, j = ll & 7;
        int w = wtile*16 + (lane & 15);
        int k = (ch % 3)*32 + ((lane>>4)&3)*8 + j;
        float coef = 0.f;
        if (k < 33){
            float s = (k==0 || k==32) ? 1.f : 2.f;
            coef = s*cosf(2.0f*PI_F*(float)(k*w)/64.0f)*(1.0f/64.0f);
        } else if (k < 66){
            int f = k - 33;
            float s = (f==0 || f==32) ? 1.f : 2.f;
            coef = -s*sinf(2.0f*PI_F*(float)(f*w)/64.0f)*(1.0f/64.0f);
        }
        unsigned short hi = f2bf(coef);
        wt[18432 + 10240 + i] = (ch < 3) ? hi : f2bf(coef - bf2f(hi));
        return;
    }
}

// ---- K1: conv1 (MFMA, bf16). Block = (l, h-tile of 2). Grid 512. ----
__global__ __launch_bounds__(256, 4) void k_conv1m(const float* __restrict__ x,
                                                   const unsigned short* __restrict__ wt,
                                                   const float* __restrict__ cb,
                                                   unsigned short* __restrict__ f1p){
    __shared__ __align__(16) unsigned short xs[4*66*32];  // rows h0-1..h0+2
    __shared__ __align__(16) unsigned short pw[9216];

    const int tid  = threadIdx.x;
    const int l    = blockIdx.x >> 5;
    const int h0   = (blockIdx.x & 31)*2;
    const int wid  = tid >> 6;
    const int lane = tid & 63;
    const int col  = lane & 15;
    const int kgrp = lane >> 4;

    {
        const unsigned int* src = (const unsigned int*)wt;
        unsigned int* dst = (unsigned int*)pw;
        #pragma unroll
        for (int j = 0; j < 18; ++j) dst[tid + j*256] = src[tid + j*256];
    }
    {
        const int rr = tid >> 6;          // 0..3 -> rows h0-1..h0+2
        const int w  = tid & 63;
        int hh = h0 - 1 + rr;
        bool hv = (hh >= 0 && hh < HH);
        const float* sp = x + (long)l*HH*WW + hh*WW + w;
        int wIdx = 1 + w;
        #pragma unroll
        for (int cib = 0; cib < 4; ++cib){
            float v[8];
            #pragma unroll
            for (int k = 0; k < 8; ++k)
                v[k] = hv ? sp[(long)(cib*8 + k)*LL*HH*WW] : 0.f;
            uint4 p;
            p.x = (unsigned)f2bf(v[0]) | ((unsigned)f2bf(v[1])<<16);
            p.y = (unsigned)f2bf(v[2]) | ((unsigned)f2bf(v[3])<<16);
            p.z = (unsigned)f2bf(v[4]) | ((unsigned)f2bf(v[5])<<16);
            p.w = (unsigned)f2bf(v[6]) | ((unsigned)f2bf(v[7])<<16);
            int cs = cib ^ (wIdx & 3);
            *(uint4*)&xs[(rr*66 + wIdx)*32 + cs*8] = p;
        }
    }
    if (tid < 32){   // halo columns
        int row = tid >> 3, rest = tid & 7;
        int wIdx = (rest >> 2) ? 65 : 0;
        int cib = rest & 3;
        *(uint4*)&xs[(row*66 + wIdx)*32 + cib*8] = make_uint4(0,0,0,0);
    }
    __syncthreads();

    #pragma unroll
    for (int u = 0; u < 4; ++u){
        int unit = wid + u*4;             // 0..15
        int hloc = unit >> 3;             // 0..1
        int rem  = unit & 7;
        int ct   = rem >> 2;
        int wt16 = rem & 3;
        int colw = wt16*16 + col;
        f32x4 acc = {0.f,0.f,0.f,0.f};
        #pragma unroll
        for (int kh = 0; kh < 3; ++kh){
            #pragma unroll
            for (int kw = 0; kw < 3; ++kw){
                int wIdx = colw + kw;
                int cs = kgrp ^ (wIdx & 3);
                short8 b = *(const short8*)&xs[((hloc+kh)*66 + wIdx)*32 + cs*8];
                short8 a = *(const short8*)&pw[((kh*3+kw)*2 + ct)*512 + lane*8];
                acc = __builtin_amdgcn_mfma_f32_16x16x32_bf16(a, b, acc, 0, 0, 0);
            }
        }
        int co0 = ct*16 + kgrp*4;
        int h = h0 + hloc;
        float o[4];
        #pragma unroll
        for (int r = 0; r < 4; ++r){
            float v = acc[r] + cb[co0+r];
            o[r] = v * sigmoidf_(v);
        }
        uint2 pk;
        pk.x = (unsigned)f2bf(o[0]) | ((unsigned)f2bf(o[1])<<16);
        pk.y = (unsigned)f2bf(o[2]) | ((unsigned)f2bf(o[3])<<16);
        *(uint2*)&f1p[(((long)l*HH + h)*WW + colw)*32 + co0] = pk;
    }
}

// ---- K2: conv2 (MFMA, bf16) -> h-pair-reduced PART. Grid 512. ----
__global__ __launch_bounds__(256, 4) void k_conv2m(const unsigned short* __restrict__ f1p,
                                                   const unsigned short* __restrict__ wt,
                                                   const float* __restrict__ cb,
                                                   float* __restrict__ ws){
    __shared__ __align__(16) unsigned short xs[4*66*32];
    __shared__ __align__(16) unsigned short pw[9216];

    const int tid  = threadIdx.x;
    const int l    = blockIdx.x >> 5;
    const int ht   = blockIdx.x & 31;
    const int h0   = ht*2;
    const int wid  = tid >> 6;
    const int lane = tid & 63;
    const int col  = lane & 15;
    const int kgrp = lane >> 4;

    {
        const unsigned int* src = (const unsigned int*)wt;
        unsigned int* dst = (unsigned int*)pw;
        #pragma unroll
        for (int j = 0; j < 18; ++j) dst[tid + j*256] = src[tid + j*256];
    }
    {
        const int rr = tid >> 6;
        const int w  = tid & 63;
        int hh = h0 - 1 + rr;
        bool hv = (hh >= 0 && hh < HH);
        const uint4* sp = (const uint4*)&f1p[(((long)l*HH + hh)*WW + w)*32];
        int wIdx = 1 + w;
        #pragma unroll
        for (int cib = 0; cib < 4; ++cib){
            uint4 p = hv ? sp[cib] : make_uint4(0,0,0,0);
            int cs = cib ^ (wIdx & 3);
            *(uint4*)&xs[(rr*66 + wIdx)*32 + cs*8] = p;
        }
    }
    if (tid < 32){
        int row = tid >> 3, rest = tid & 7;
        int wIdx = (rest >> 2) ? 65 : 0;
        int cib = rest & 3;
        *(uint4*)&xs[(row*66 + wIdx)*32 + cib*8] = make_uint4(0,0,0,0);
    }
    __syncthreads();

    // p=0,1: same (ct,wt16) for both hloc -> silu(h0)+silu(h1) in registers
    #pragma unroll
    for (int p = 0; p < 2; ++p){
        int rem  = wid + p*4;            // 0..7
        int ct   = rem >> 2;
        int wt16 = rem & 3;
        int colw = wt16*16 + col;
        f32x4 acc0 = {0.f,0.f,0.f,0.f};
        f32x4 acc1 = {0.f,0.f,0.f,0.f};
        #pragma unroll
        for (int kh = 0; kh < 3; ++kh){
            #pragma unroll
            for (int kw = 0; kw < 3; ++kw){
                int wIdx = colw + kw;
                int cs = kgrp ^ (wIdx & 3);
                short8 a  = *(const short8*)&pw[((kh*3+kw)*2 + ct)*512 + lane*8];
                short8 b0 = *(const short8*)&xs[((0+kh)*66 + wIdx)*32 + cs*8];
                short8 b1 = *(const short8*)&xs[((1+kh)*66 + wIdx)*32 + cs*8];
                acc0 = __builtin_amdgcn_mfma_f32_16x16x32_bf16(a, b0, acc0, 0, 0, 0);
                acc1 = __builtin_amdgcn_mfma_f32_16x16x32_bf16(a, b1, acc1, 0, 0, 0);
            }
        }
        int co0 = ct*16 + kgrp*4;
        float* pp = ws + OFF_PART + ((long)(l*32 + ht))*2048 + colw;
        #pragma unroll
        for (int r = 0; r < 4; ++r){
            float bias = cb[co0+r];
            float v0 = acc0[r] + bias; v0 = v0 * sigmoidf_(v0);
            float v1 = acc1[r] + bias; v1 = v1 * sigmoidf_(v1);
            pp[(co0+r)*WW] = v0 + v1;
        }
    }
}

// ---- K2b: colsum (LDS-only) + glob + adaptive pool, fused. Block = l. ----
__global__ void k_colglob(const float* __restrict__ gfc_w, const float* __restrict__ gfc_b,
                          float* __restrict__ ws){
    __shared__ float colsum[CC*WW];      // [c][w]
    __shared__ float gs[CC], gl[CC];
    int l = blockIdx.x;
    int tid = threadIdx.x;
    const float4* p4 = (const float4*)(ws + OFF_PART + (long)l*32*2048);
    #pragma unroll
    for (int s = 0; s < 2; ++s){
        int idx = tid + s*256;           // float4 index 0..511
        float4 acc = {0.f,0.f,0.f,0.f};
        #pragma unroll 8
        for (int ht = 0; ht < 32; ++ht){
            float4 v = p4[ht*512 + idx];
            acc.x += v.x; acc.y += v.y; acc.z += v.z; acc.w += v.w;
        }
        *(float4*)&colsum[idx*4] = acc;
    }
    __syncthreads();
    if (tid < 32){
        const float* cs = colsum + tid*WW;
        float s = 0.f;
        for (int w=0;w<WW;w++) s += cs[w];
        gs[tid] = s;
    }
    __syncthreads();
    if (tid < 32){
        float acc = gfc_b[tid];
        for (int i=0;i<CC;i++) acc += gs[i]*(1.0f/4096.0f)*gfc_w[tid*CC+i];
        gl[tid] = sigmoidf_(acc);
    }
    __syncthreads();
    for (int i = tid; i < WF*CC; i += 256){
        int c = i & 31, wf = i >> 5;
        int s = (wf*64)/33;
        int e = ((wf+1)*64 + 32)/33;
        const float* cs = colsum + c*WW;
        float sum = 0.f;
        for (int w=s;w<e;w++) sum += cs[w];
        ws[OFF_FEAT + (l*WF+wf)*CC + c] = gl[c] * sum / (64.0f*(float)(e-s));
    }
}

// ---- K6: rfft via MFMA -> packed bf16 complex XF. Block=(l,c). ----
__global__ __launch_bounds__(256, 4) void k_rfftm(const float* __restrict__ x,
                                                  const unsigned short* __restrict__ at,
                                                  float* __restrict__ ws){
    __shared__ __align__(16) unsigned short xs[HH*68];
    __shared__ float fre[33*64];
    __shared__ float fim[33*64];
    int b = blockIdx.x; int l = b >> 5, c = b & 31;
    int tid = threadIdx.x;
    const int wid  = tid >> 6;
    const int lane = tid & 63;
    const int col  = lane & 15;
    const int kgrp = lane >> 4;

    const float* xp = x + (long)(c*LL + l)*HH*WW;
    for (int i = tid; i < HH*WW; i += 256){
        int h = i >> 6, w = i & 63;
        xs[h*68 + w] = f2bf(xp[i]);
    }
    __syncthreads();

    #pragma unroll
    for (int q = 0; q < 5; ++q){
        int unit = wid + q*4;
        int ftile = unit >> 2;
        int htile = unit & 3;
        f32x4 acc = {0.f,0.f,0.f,0.f};
        #pragma unroll
        for (int cch = 0; cch < 4; ++cch){
            short8 a = *(const short8*)&at[(((ftile*4 + cch)*64) + lane)*8];
            short8 bb = *(const short8*)&xs[(htile*16 + col)*68 + (cch & 1)*32 + kgrp*8];
            acc = __builtin_amdgcn_mfma_f32_16x16x32_bf16(a, bb, acc, 0, 0, 0);
        }
        int h = htile*16 + col;
        #pragma unroll
        for (int r = 0; r < 4; ++r){
            int fr = ftile*16 + kgrp*4 + r;
            if (fr < 33)      fre[fr*64 + h] = acc[r];
            else if (fr < 66) fim[(fr-33)*64 + h] = acc[r];
        }
    }
    __syncthreads();
    unsigned* xfp = (unsigned*)(ws + OFF_XFR) + (long)(l*CC + c)*2112;
    for (int i = tid; i < 2112; i += 256){
        xfp[i] = (unsigned)f2bf(fre[i]) | ((unsigned)f2bf(fim[i]) << 16);
    }
}

// ---- K7: scan over L, HEAD FUSED IN. Packed bf16 complex XF/YF. Block=(c,wf). ----
__global__ __launch_bounds__(256) void k_scan(const float* __restrict__ hw,
                                              const float* __restrict__ hb,
                                              const float* __restrict__ dt,
                                              float* __restrict__ ws){
    __shared__ float lA[LL*RR], lI[LL*RR], lS[LL*RR];
    __shared__ float wv[66];
    __shared__ float lfeat[LL*CC];
    int b = blockIdx.x;
    int c = b / WF, f = b - c*WF;
    int tid = threadIdx.x;
    if (tid < 66) wv[tid] = ws[OFF_WVEC + tid];
    for (int i = tid; i < LL*CC; i += 256){
        int l = i >> 5, ii = i & 31;
        lfeat[i] = ws[OFF_FEAT + (l*WF + f)*CC + ii];
    }
    __syncthreads();
    {
        int l = tid >> 4, r = tid & 15;
        const float* feat = lfeat + l*CC;
        int j0 = (c*RR + r)*3;
        const float* w0 = hw + j0*CC;
        float p0=hb[j0], p1=hb[j0+1], p2=hb[j0+2];
        #pragma unroll 8
        for (int i=0;i<CC;i++){
            float fv = feat[i];
            p0 += fv*w0[i]; p1 += fv*w0[CC+i]; p2 += fv*w0[2*CC+i];
        }
        float nu = fmaxf(p0,0.f) + log1pf(expf(-fabsf(p0)));
        float th = tanhf(p1)*PI_F;
        float sg = sigmoidf_(p2);
        float dtv = dt[l];
        float decay = expf(-nu*dtv);
        float ang = th*dtv;
        lA[tid] = decay*cosf(ang);
        lI[tid] = decay*sinf(ang);
        lS[tid] = sg*(1.0f - expf(-2.0f*fmaxf(dtv,0.f)));
    }
    __syncthreads();
    const int h  = tid >> 2;
    const int rq = tid & 3;
    float sre[4] = {0,0,0,0}, sim[4] = {0,0,0,0};
    float w0_[4], w1_[4], w2_[4], w3_[4];
    #pragma unroll
    for (int q=0;q<4;q++){
        int r = rq*4 + q;
        w0_[q]=wv[r]; w1_[q]=wv[16+r]; w2_[q]=wv[32+r]; w3_[q]=wv[48+r];
    }
    const float cre = wv[64], cim = wv[65];
    const long fh = (long)(c*WF + f)*HH + h;
    const unsigned* xfp = (const unsigned*)(ws + OFF_XFR);
    unsigned* yfp = (unsigned*)(ws + OFF_YFR);
    #pragma unroll 2
    for (int l=0;l<LL;l++){
        unsigned px = xfp[l*(CC*HH*WF) + fh];
        float xr = bf2f((unsigned short)(px & 0xffffu));
        float xi = bf2f((unsigned short)(px >> 16));
        float yr = 0.f, yi = 0.f;
        #pragma unroll
        for (int q=0;q<4;q++){
            int r = rq*4 + q;
            float a = lA[l*16+r], ii = lI[l*16+r], s = lS[l*16+r];
            float nre = a*sre[q] - ii*sim[q] + s*xr;
            float nim = a*sim[q] + ii*sre[q] + s*xi;
            sre[q]=nre; sim[q]=nim;
            yr += w0_[q]*nre + w1_[q]*nim;
            yi += w2_[q]*nre + w3_[q]*nim;
        }
        yr += __shfl_xor(yr, 1); yr += __shfl_xor(yr, 2);
        yi += __shfl_xor(yi, 1); yi += __shfl_xor(yi, 2);
        if (rq == 0){
            yfp[l*(CC*HH*WF) + fh] =
                (unsigned)f2bf(yr + cre) | ((unsigned)f2bf(yi + cim) << 16);
        }
    }
}

// ---- K8: irfft via MFMA from packed bf16 YF. Block=(l,c). ----
__global__ __launch_bounds__(256, 4) void k_irfftm(const unsigned short* __restrict__ btb,
                                                   float* __restrict__ ws){
    __shared__ __align__(16) unsigned short mh[HH*100];
    int b = blockIdx.x; int l = b >> 5, c = b & 31;
    int tid = threadIdx.x;
    const int wid  = tid >> 6;
    const int lane = tid & 63;
    const int col  = lane & 15;
    const int kgrp = lane >> 4;

    const unsigned* yfp = (const unsigned*)(ws + OFF_YFR) + (long)(l*CC + c)*2112;
    for (int i = tid; i < 2112; i += 256){
        unsigned p = yfp[i];
        int f = i >> 6, h = i & 63;
        mh[h*100 + f]      = (unsigned short)(p & 0xffffu);
        mh[h*100 + 33 + f] = (unsigned short)(p >> 16);
    }
    for (int i = tid; i < 64*34; i += 256){
        int h = i / 34, f = 66 + (i - (i/34)*34);
        mh[h*100 + f] = 0;
    }
    __syncthreads();

    float* y1 = ws + OFF_Y1 + (long)(l*CC + c)*HH*WW;
    #pragma unroll
    for (int q = 0; q < 4; ++q){
        int unit = wid + q*4;
        int htile = unit >> 2;
        int wtile = unit & 3;
        f32x4 acc = {0.f,0.f,0.f,0.f};
        #pragma unroll
        for (int ch = 0; ch < 6; ++ch){
            int kof = (ch % 3)*32 + kgrp*8;
            short8 a = *(const short8*)&mh[(htile*16 + col)*100 + kof];
            short8 bb = *(const short8*)&btb[(((wtile*6 + ch)*64) + lane)*8];
            acc = __builtin_amdgcn_mfma_f32_16x16x32_bf16(a, bb, acc, 0, 0, 0);
        }
        int w = wtile*16 + col;
        #pragma unroll
        for (int r = 0; r < 4; ++r){
            int h = htile*16 + kgrp*4 + r;
            y1[h*WW + w] = acc[r];
        }
    }
}

// ---- K9: pif + raw W-mean (YM) + row sum-of-squares (YQ). Block = (l,h).
//      Register-column reuse: 32 LDS reads/thread, then 8x32 reg-FMAs. ----
__global__ void k_pif(const float* __restrict__ pw, const float* __restrict__ pb,
                      float* __restrict__ ws){
    __shared__ float row[CC][WW];
    int b = blockIdx.x; int l = b>>6, h = b&63;
    int tid = threadIdx.x;
    for (int k=0;k<8;k++){
        int i = tid + k*256;
        int ci = i>>6, w = i&63;
        row[ci][w] = ws[OFF_Y1 + ((l*CC+ci)*HH + h)*WW + w];
    }
    __syncthreads();
    const int w = tid & 63;
    float xv[CC];
    #pragma unroll
    for (int ci = 0; ci < CC; ++ci) xv[ci] = row[ci][w];   // lane==w: conflict-free
    #pragma unroll
    for (int k=0;k<8;k++){
        int o = (tid>>6) + k*4;              // wave-uniform
        float acc = pb[o];
        #pragma unroll
        for (int ci=0;ci<CC;ci++) acc += pw[o*CC+ci]*xv[ci];
        ws[OFF_Y2 + ((l*CC+o)*HH + h)*WW + w] = acc;
        float s = acc, q = acc*acc;
        s += __shfl_down(s, 32, 64); q += __shfl_down(q, 32, 64);
        s += __shfl_down(s, 16, 64); q += __shfl_down(q, 16, 64);
        s += __shfl_down(s,  8, 64); q += __shfl_down(q,  8, 64);
        s += __shfl_down(s,  4, 64); q += __shfl_down(q,  4, 64);
        s += __shfl_down(s,  2, 64); q += __shfl_down(q,  2, 64);
        s += __shfl_down(s,  1, 64); q += __shfl_down(q,  1, 64);
        if ((tid & 63) == 0){
            ws[OFF_YM + (l*HH+h)*CC + o] = s*(1.0f/64.0f);
            ws[OFF_YQ + (l*HH+h)*CC + o] = q;
        }
    }
}

// ---- K12: gate, with GN stats fused (per-l, per-h-quad). Grid 64. ----
__global__ void k_gatel(const float* __restrict__ g1w, const float* __restrict__ g1b,
                        const float* __restrict__ g2w, const float* __restrict__ g2b,
                        const float* __restrict__ gnw, const float* __restrict__ gnb,
                        float* __restrict__ ws){
    __shared__ float mus[4], rsd[4];
    __shared__ float ymn[16][CC+1];
    __shared__ float mid[16][4];
    int blk = blockIdx.x;
    int l = blk >> 2, hq = blk & 3;
    int h0 = hq*16;
    int tid = threadIdx.x;

    {
        int g = tid >> 6, j = tid & 63;
        const float* ymp = ws + OFF_YM + (l*HH + j)*CC + g*8;
        const float* yqp = ws + OFF_YQ + (l*HH + j)*CC + g*8;
        float s = 0.f, q = 0.f;
        #pragma unroll
        for (int cc = 0; cc < 8; ++cc){ s += ymp[cc]; q += yqp[cc]; }
        #pragma unroll
        for (int off = 32; off > 0; off >>= 1){
            s += __shfl_down(s, off, 64);
            q += __shfl_down(q, off, 64);
        }
        if (j == 0){
            float mean = s*(1.0f/512.0f);
            float rstd = rsqrtf(q*(1.0f/32768.0f) - mean*mean + 1e-5f);
            mus[g] = mean; rsd[g] = rstd;
            if (hq == 0){ ws[OFF_GNM + l*4+g] = mean; ws[OFF_GNR + l*4+g] = rstd; }
        }
    }
    __syncthreads();
    for (int i = tid; i < 16*CC; i += 256){
        int hh = i >> 5, cidx = i & 31;
        int g = cidx >> 3;
        ymn[hh][cidx] = (ws[OFF_YM + (l*HH + h0 + hh)*CC + cidx] - mus[g])*rsd[g]*gnw[cidx] + gnb[cidx];
    }
    __syncthreads();
    if (tid < 64){
        int hh = tid >> 2, m = tid & 3;
        float a = g1b[m];
        #pragma unroll 8
        for (int i = 0; i < CC; ++i) a += ymn[hh][i]*g1w[m*CC+i];
        mid[hh][m] = a*sigmoidf_(a);
    }
    __syncthreads();
    for (int i = tid; i < 16*CC; i += 256){
        int hh = i >> 5, cidx = i & 31;
        float a = g2b[cidx];
        #pragma unroll
        for (int m = 0; m < 4; ++m) a += mid[hh][m]*g2w[cidx*4+m];
        ws[OFF_GATE + (l*HH + h0 + hh)*CC + cidx] = sigmoidf_(a);
    }
}

// ---- K13: residual (float4), GN applied inline on raw Y2 ----
__global__ void k_final(const float* __restrict__ x, float* __restrict__ out,
                        const float* __restrict__ gnw, const float* __restrict__ gnb,
                        const float* __restrict__ ws){
    int t = blockIdx.x*256 + threadIdx.x;
    int n = t*4;
    int h = (n>>6)&63, l = (n>>12)&15, c = n>>16;
    int g = c>>3;
    float mu = ws[OFF_GNM + l*4+g], rstd = ws[OFF_GNR + l*4+g];
    float gw = gnw[c]*rstd, gb = gnb[c] - mu*gnw[c]*rstd;
    float4 z  = *(const float4*)(ws + OFF_Y2 + (((l*CC+c)*HH+h)*WW) + (n&63));
    float  gt = ws[OFF_GATE + (l*HH+h)*CC + c];
    float4 xv = *(const float4*)(x + n);
    float4 o;
    o.x = xv.x + (z.x*gw+gb)*gt; o.y = xv.y + (z.y*gw+gb)*gt;
    o.z = xv.z + (z.z*gw+gb)*gt; o.w = xv.w + (z.w*gw+gb)*gt;
    *(float4*)(out + n) = o;
}

extern "C" void kernel_launch(void* const* d_in, const int* in_sizes, int n_in,
                              void* d_out, int out_size, void* d_ws, size_t ws_size,
                              hipStream_t stream){
    const float* x    = (const float*)d_in[0];
    const float* dt   = (const float*)d_in[1];
    const float* c1w  = (const float*)d_in[2];
    const float* c1b  = (const float*)d_in[3];
    const float* c2w  = (const float*)d_in[4];
    const float* c2b  = (const float*)d_in[5];
    const float* gfcw = (const float*)d_in[6];
    const float* gfcb = (const float*)d_in[7];
    const float* hw   = (const float*)d_in[8];
    const float* hb   = (const float*)d_in[9];
    const float* mixw = (const float*)d_in[10];
    const float* mixb = (const float*)d_in[11];
    const float* rs   = (const float*)d_in[12];
    const float* pjw  = (const float*)d_in[13];
    const float* pjb  = (const float*)d_in[14];
    const float* pifw = (const float*)d_in[15];
    const float* pifb = (const float*)d_in[16];
    const float* gnw  = (const float*)d_in[17];
    const float* gnb  = (const float*)d_in[18];
    const float* g1w  = (const float*)d_in[19];
    const float* g1b  = (const float*)d_in[20];
    const float* g2w  = (const float*)d_in[21];
    const float* g2b  = (const float*)d_in[22];
    float* ws  = (float*)d_ws;
    float* out = (float*)d_out;
    unsigned short* wt  = (unsigned short*)(ws + OFF_WT);
    unsigned short* at  = wt + 18432;
    unsigned short* btb = wt + 18432 + 10240;
    unsigned short* f1p = (unsigned short*)(ws + OFF_F1);

    k_prep0   <<<161,  256, 0, stream>>>(mixw, mixb, rs, pjw, pjb, c1w, c2w, ws);
    k_conv1m  <<<512,  256, 0, stream>>>(x, wt, c1b, f1p);
    k_conv2m  <<<512,  256, 0, stream>>>(f1p, wt + 9216, c2b, ws);
    k_colglob <<<16,   256, 0, stream>>>(gfcw, gfcb, ws);
    k_rfftm   <<<512,  256, 0, stream>>>(x, at, ws);
    k_scan    <<<1056, 256, 0, stream>>>(hw, hb, dt, ws);
    k_irfftm  <<<512,  256, 0, stream>>>(btb, ws);
    k_pif     <<<1024, 256, 0, stream>>>(pifw, pifb, ws);
    k_gatel   <<<64,   256, 0, stream>>>(g1w, g1b, g2w, g2b, gnw, gnb, ws);
    k_final   <<<2048, 256, 0, stream>>>(x, out, gnw, gnb, ws);
}